// Round 4
// baseline (386.088 us; speedup 1.0000x reference)
//
#include <hip/hip_runtime.h>
#include <stdint.h>

typedef unsigned short u16;
typedef unsigned int   u32;

#define HW   16384      // 128*128
#define NPIX 131072     // 8 * HW

__device__ __forceinline__ float sigm(float x) { return 1.f / (1.f + __expf(-x)); }

// Inputs float32 (Round-2 NaN ruled out bf16 inputs); output float32
// (Round-3 absmax-4.03 signature ruled out bf16 output packing; harness
// contract: out dtype = reference output dtype = float32).
__global__ __launch_bounds__(256) void half_graph_fused(
    const float* __restrict__ hf,  const float* __restrict__ xhu, const float* __restrict__ xhl,
    const float* __restrict__ xfg, const float* __restrict__ xpg,
    const float* __restrict__ pdp_w1, const float* __restrict__ pdp_w2,
    const float* __restrict__ att_w,  const float* __restrict__ att_b,
    const float* __restrict__ cU_aw, const float* __restrict__ cU_ab, const float* __restrict__ cU_w,
    const float* __restrict__ cL_aw, const float* __restrict__ cL_ab, const float* __restrict__ cL_w,
    const float* __restrict__ dU_aw, const float* __restrict__ dU_ab, const float* __restrict__ dU_w,
    const float* __restrict__ dL_aw, const float* __restrict__ dL_ab, const float* __restrict__ dL_w,
    const float* __restrict__ uU_gw, const float* __restrict__ uU_gb, const float* __restrict__ uU_cw,
    const float* __restrict__ uL_gw, const float* __restrict__ uL_gb, const float* __restrict__ uL_cw,
    float* __restrict__ out)
{
    const int p  = blockIdx.x * blockDim.x + threadIdx.x;   // pixel id
    const int n  = p >> 14;            // batch (wave-uniform)
    const int hw = p & 16383;          // spatial (lane-contiguous)

    // ---------------- big matvec over h_fea: 22 dots of length 256 ----------
    const float* hfp = hf + (size_t)n * 256 * HW + hw;

    float accT[20];
    #pragma unroll
    for (int o = 0; o < 20; ++o) accT[o] = 0.f;
    float dU = 0.f, dL = 0.f;

    #pragma unroll 8
    for (int c = 0; c < 256; ++c) {
        float x = hfp[c * HW];   // 4B/lane, 256B/wave coalesced
        #pragma unroll
        for (int o = 0; o < 20; ++o) accT[o] = fmaf(pdp_w1[o * 276 + c], x, accT[o]);
        dU = fmaf(dU_aw[c], x, dU);
        dL = fmaf(dL_aw[c], x, dL);
    }

    // ---------------- small per-pixel vectors -------------------------------
    float xu[10], xl[10], xv[10];
    {
        const float* a = xhu + (size_t)n * 10 * HW + hw;
        const float* b = xhl + (size_t)n * 10 * HW + hw;
        const float* c = xfg + (size_t)n * 10 * HW + hw;
        #pragma unroll
        for (int i = 0; i < 10; ++i) xu[i] = a[i * HW];
        #pragma unroll
        for (int i = 0; i < 10; ++i) xl[i] = b[i * HW];
        #pragma unroll
        for (int i = 0; i < 10; ++i) xv[i] = c[i * HW];
    }

    // ---------------- pdp: t = relu(W1 @ [hf,xu,xl]) ------------------------
    float t[20];
    #pragma unroll
    for (int o = 0; o < 20; ++o) {
        float s = accT[o];
        #pragma unroll
        for (int i = 0; i < 10; ++i) s = fmaf(pdp_w1[o * 276 + 256 + i], xu[i], s);
        #pragma unroll
        for (int i = 0; i < 10; ++i) s = fmaf(pdp_w1[o * 276 + 266 + i], xl[i], s);
        t[o] = fmaxf(s, 0.f);
    }
    // dp = relu(gconv(t, pdp_w2)); dp_u = dp[0:10], dp_l = dp[10:20]
    float dpv[20];
    #pragma unroll
    for (int g = 0; g < 2; ++g) {
        #pragma unroll
        for (int o = 0; o < 10; ++o) {
            float s = 0.f;
            #pragma unroll
            for (int i = 0; i < 10; ++i)
                s = fmaf(pdp_w2[(g * 10 + o) * 10 + i], t[g * 10 + i], s);
            dpv[g * 10 + o] = fmaxf(s, 0.f);
        }
    }

    // ---------------- a = sigmoid(gconv([xu,xl], att_w, att_b)) -------------
    float au_s = att_b[0], al_s = att_b[1];
    #pragma unroll
    for (int i = 0; i < 10; ++i) {
        au_s = fmaf(att_w[i], xu[i], au_s);
        al_s = fmaf(att_w[10 + i], xl[i], al_s);
    }
    const float au = sigm(au_s), al = sigm(al_s);

    // ---------------- decomp attention scalars: [h_fea | xf | xh] -----------
    float su = dU + dU_ab[0];
    float sl = dL + dL_ab[0];
    #pragma unroll
    for (int i = 0; i < 10; ++i) { su = fmaf(dU_aw[256 + i], xv[i], su); sl = fmaf(dL_aw[256 + i], xv[i], sl); }
    #pragma unroll
    for (int i = 0; i < 10; ++i) { su = fmaf(dU_aw[266 + i], xu[i], su); sl = fmaf(dL_aw[266 + i], xl[i], sl); }
    const float attU = sigm(su), attL = sigm(sl);

    // xfh = relu(att * (W @ xf))
    float xfhu[10], xfhl[10];
    #pragma unroll
    for (int o = 0; o < 10; ++o) {
        float a = 0.f, b = 0.f;
        #pragma unroll
        for (int i = 0; i < 10; ++i) {
            a = fmaf(dU_w[o * 10 + i], xv[i], a);
            b = fmaf(dL_w[o * 10 + i], xv[i], b);
        }
        xfhu[o] = fmaxf(attU * a, 0.f);
        xfhl[o] = fmaxf(attL * b, 0.f);
    }

    // ---------------- comp U (xp[0:4]) --------------------------------------
    float msgU[10];
    #pragma unroll
    for (int i = 0; i < 10; ++i) msgU[i] = 0.f;
    #pragma unroll
    for (int pp = 0; pp < 4; ++pp) {
        const float* xq = xpg + (size_t)(pp * 8 + n) * 10 * HW + hw;
        float v[10];
        #pragma unroll
        for (int i = 0; i < 10; ++i) v[i] = xq[i * HW];
        float s = cU_ab[pp];
        #pragma unroll
        for (int i = 0; i < 10; ++i) s = fmaf(cU_aw[pp * 10 + i], v[i], s);
        float ca = sigm(s);
        #pragma unroll
        for (int i = 0; i < 10; ++i) msgU[i] = fmaf(ca, v[i], msgU[i]);
    }
    float xphu[10];
    #pragma unroll
    for (int o = 0; o < 10; ++o) {
        float s = 0.f;
        #pragma unroll
        for (int i = 0; i < 10; ++i) s = fmaf(cU_w[o * 20 + i], xu[i], s);
        #pragma unroll
        for (int i = 0; i < 10; ++i) s = fmaf(cU_w[o * 20 + 10 + i], msgU[i], s);
        xphu[o] = fmaxf(s, 0.f);
    }

    // ---------------- comp L (xp[4:6]) --------------------------------------
    float msgL[10];
    #pragma unroll
    for (int i = 0; i < 10; ++i) msgL[i] = 0.f;
    #pragma unroll
    for (int pp = 4; pp < 6; ++pp) {
        const float* xq = xpg + (size_t)(pp * 8 + n) * 10 * HW + hw;
        float v[10];
        #pragma unroll
        for (int i = 0; i < 10; ++i) v[i] = xq[i * HW];
        float s = cL_ab[pp - 4];
        #pragma unroll
        for (int i = 0; i < 10; ++i) s = fmaf(cL_aw[(pp - 4) * 10 + i], v[i], s);
        float ca = sigm(s);
        #pragma unroll
        for (int i = 0; i < 10; ++i) msgL[i] = fmaf(ca, v[i], msgL[i]);
    }
    float xphl[10];
    #pragma unroll
    for (int o = 0; o < 10; ++o) {
        float s = 0.f;
        #pragma unroll
        for (int i = 0; i < 10; ++i) s = fmaf(cL_w[o * 20 + i], xl[i], s);
        #pragma unroll
        for (int i = 0; i < 10; ++i) s = fmaf(cL_w[o * 20 + 10 + i], msgL[i], s);
        xphl[o] = fmaxf(s, 0.f);
    }

    // ---------------- updates ----------------------------------------------
    float outU[10], outL[10];
    {
        float m[10];
        #pragma unroll
        for (int i = 0; i < 10; ++i)
            m[i] = xphu[i] + (dpv[10 + i] * al + xu[i] * au) + xfhu[i];  // xlh = dp_l*a_l + xh_u*a_u
        #pragma unroll
        for (int o = 0; o < 10; ++o) {
            float gs = uU_gb[o], cs = 0.f;
            #pragma unroll
            for (int i = 0; i < 10; ++i) {
                gs = fmaf(uU_gw[o * 20 + i], xu[i], gs);
                cs = fmaf(uU_cw[o * 20 + i], xu[i], cs);
            }
            #pragma unroll
            for (int i = 0; i < 10; ++i) {
                gs = fmaf(uU_gw[o * 20 + 10 + i], m[i], gs);
                cs = fmaf(uU_cw[o * 20 + 10 + i], m[i], cs);
            }
            float g = sigm(gs), cd = fmaxf(cs, 0.f);
            outU[o] = xu[o] * (1.f - g) + cd * g;
        }
    }
    {
        float m[10];
        #pragma unroll
        for (int i = 0; i < 10; ++i)
            m[i] = xphl[i] + (dpv[i] * au + xl[i] * al) + xfhl[i];       // xuh = dp_u*a_u + xh_l*a_l
        #pragma unroll
        for (int o = 0; o < 10; ++o) {
            float gs = uL_gb[o], cs = 0.f;
            #pragma unroll
            for (int i = 0; i < 10; ++i) {
                gs = fmaf(uL_gw[o * 20 + i], xl[i], gs);
                cs = fmaf(uL_cw[o * 20 + i], xl[i], cs);
            }
            #pragma unroll
            for (int i = 0; i < 10; ++i) {
                gs = fmaf(uL_gw[o * 20 + 10 + i], m[i], gs);
                cs = fmaf(uL_cw[o * 20 + 10 + i], m[i], cs);
            }
            float g = sigm(gs), cd = fmaxf(cs, 0.f);
            outL[o] = xl[o] * (1.f - g) + cd * g;
        }
    }

    // ---------------- stores: [xh_u_new | xh_l_new | att_u | att_l] (f32) ---
    {
        int baseU = n * 10 * HW + hw;
        #pragma unroll
        for (int c = 0; c < 10; ++c) out[baseU + c * HW] = outU[c];
        int baseL = 1310720 + baseU;
        #pragma unroll
        for (int c = 0; c < 10; ++c) out[baseL + c * HW] = outL[c];
        out[2621440 + n * HW + hw] = attU;
        out[2752512 + n * HW + hw] = attL;
    }
}

extern "C" void kernel_launch(void* const* d_in, const int* in_sizes, int n_in,
                              void* d_out, int out_size, void* d_ws, size_t ws_size,
                              hipStream_t stream) {
    (void)in_sizes; (void)n_in; (void)out_size; (void)d_ws; (void)ws_size;
    const float* hf   = (const float*)d_in[0];
    const float* xhu  = (const float*)d_in[1];
    const float* xhl  = (const float*)d_in[2];
    const float* xfg  = (const float*)d_in[3];
    const float* xpg  = (const float*)d_in[4];
    const float* w1   = (const float*)d_in[5];
    const float* w2   = (const float*)d_in[6];
    const float* aw   = (const float*)d_in[7];
    const float* ab   = (const float*)d_in[8];
    const float* cUaw = (const float*)d_in[9];
    const float* cUab = (const float*)d_in[10];
    const float* cUw  = (const float*)d_in[11];
    const float* cLaw = (const float*)d_in[12];
    const float* cLab = (const float*)d_in[13];
    const float* cLw  = (const float*)d_in[14];
    const float* dUaw = (const float*)d_in[15];
    const float* dUab = (const float*)d_in[16];
    const float* dUw  = (const float*)d_in[17];
    const float* dLaw = (const float*)d_in[18];
    const float* dLab = (const float*)d_in[19];
    const float* dLw  = (const float*)d_in[20];
    const float* uUgw = (const float*)d_in[21];
    const float* uUgb = (const float*)d_in[22];
    const float* uUcw = (const float*)d_in[23];
    const float* uLgw = (const float*)d_in[24];
    const float* uLgb = (const float*)d_in[25];
    const float* uLcw = (const float*)d_in[26];

    dim3 grid(NPIX / 256), block(256);
    hipLaunchKernelGGL(half_graph_fused, grid, block, 0, stream,
        hf, xhu, xhl, xfg, xpg, w1, w2, aw, ab,
        cUaw, cUab, cUw, cLaw, cLab, cLw,
        dUaw, dUab, dUw, dLaw, dLab, dLw,
        uUgw, uUgb, uUcw, uLgw, uLgb, uLcw,
        (float*)d_out);
}

// Round 5
// 303.961 us; speedup vs baseline: 1.2702x; 1.2702x over previous
//
#include <hip/hip_runtime.h>
#include <stdint.h>

typedef unsigned short u16;
typedef unsigned int   u32;

#define HW   16384      // 128*128
#define NPIX 131072     // 8 * HW

__device__ __forceinline__ float sigm(float x) { return 1.f / (1.f + __expf(-x)); }

// Round-4 post-mortem: 1 px/thread was latency-bound (2 waves/SIMD, VALUBusy 23%,
// HBM 6.8%). This version: block=256thr/4 waves per 64 px; wave w does channels
// [64w,64w+64) of the 22 long dot-products (20 pdp rows + dU/dL att rows) with
// weights staged in LDS ([c][o] pad-24, 16B-aligned rows -> ds_read_b128
// broadcast); partials reduced via aliased LDS; wave 0 runs the per-pixel tail.
__global__ __launch_bounds__(256) void half_graph_fused(
    const float* __restrict__ hf,  const float* __restrict__ xhu, const float* __restrict__ xhl,
    const float* __restrict__ xfg, const float* __restrict__ xpg,
    const float* __restrict__ pdp_w1, const float* __restrict__ pdp_w2,
    const float* __restrict__ att_w,  const float* __restrict__ att_b,
    const float* __restrict__ cU_aw, const float* __restrict__ cU_ab, const float* __restrict__ cU_w,
    const float* __restrict__ cL_aw, const float* __restrict__ cL_ab, const float* __restrict__ cL_w,
    const float* __restrict__ dU_aw, const float* __restrict__ dU_ab, const float* __restrict__ dU_w,
    const float* __restrict__ dL_aw, const float* __restrict__ dL_ab, const float* __restrict__ dL_w,
    const float* __restrict__ uU_gw, const float* __restrict__ uU_gb, const float* __restrict__ uU_cw,
    const float* __restrict__ uL_gw, const float* __restrict__ uL_gb, const float* __restrict__ uL_cw,
    float* __restrict__ out)
{
    __shared__ float lds[256 * 24];      // phase1: W[c][o], o padded to 24 (24.6 kB)
                                         // phase2 (aliased): red[o][w][px] = 22*4*64

    const int tid = threadIdx.x;
    const int wv  = tid >> 6;            // wave 0..3 -> channel quarter
    const int ln  = tid & 63;            // lane -> pixel within block
    const int p   = blockIdx.x * 64 + ln;// global pixel
    const int n   = p >> 14;             // batch (uniform in block: 64 | 16384)
    const int hw  = p & 16383;

    // ---- stage 22x256 weight rows into LDS: rows 0..19 = pdp_w1[o][0:256],
    //      row 20 = dU_aw[0:256], row 21 = dL_aw[0:256] ----
    for (int idx = tid; idx < 22 * 256; idx += 256) {
        int o = idx >> 8, c = idx & 255;
        float w = (o < 20) ? pdp_w1[o * 276 + c]
                           : (o == 20 ? dU_aw[c] : dL_aw[c]);
        lds[c * 24 + o] = w;
    }
    __syncthreads();

    // ---- main: wave wv accumulates channels [64*wv, 64*wv+64) ----
    const float* hfp = hf + ((size_t)n * 256 + wv * 64) * HW + hw;
    float acc[22];
    #pragma unroll
    for (int o = 0; o < 22; ++o) acc[o] = 0.f;

    #pragma unroll 8
    for (int cc = 0; cc < 64; ++cc) {
        float x = hfp[cc * HW];                       // 256B/wave coalesced
        const float* wr = &lds[(wv * 64 + cc) * 24];  // uniform broadcast row
        #pragma unroll
        for (int o = 0; o < 22; ++o) acc[o] = fmaf(wr[o], x, acc[o]);
    }
    __syncthreads();   // all waves done reading weights

    // ---- write partials (conflict-free: lanes consecutive) ----
    #pragma unroll
    for (int o = 0; o < 22; ++o) lds[o * 256 + wv * 64 + ln] = acc[o];
    __syncthreads();

    if (wv != 0) return;

    // ---- reduce 4 partials per (o, px) ----
    float accT[22];
    #pragma unroll
    for (int o = 0; o < 22; ++o)
        accT[o] = (lds[o * 256 + ln]       + lds[o * 256 + 64 + ln])
                + (lds[o * 256 + 128 + ln] + lds[o * 256 + 192 + ln]);
    const float dU = accT[20], dL = accT[21];

    // ---------------- small per-pixel vectors -------------------------------
    float xu[10], xl[10], xv[10];
    {
        const float* a = xhu + (size_t)n * 10 * HW + hw;
        const float* b = xhl + (size_t)n * 10 * HW + hw;
        const float* c = xfg + (size_t)n * 10 * HW + hw;
        #pragma unroll
        for (int i = 0; i < 10; ++i) xu[i] = a[i * HW];
        #pragma unroll
        for (int i = 0; i < 10; ++i) xl[i] = b[i * HW];
        #pragma unroll
        for (int i = 0; i < 10; ++i) xv[i] = c[i * HW];
    }

    // ---------------- pdp: t = relu(W1 @ [hf,xu,xl]) ------------------------
    float t[20];
    #pragma unroll
    for (int o = 0; o < 20; ++o) {
        float s = accT[o];
        #pragma unroll
        for (int i = 0; i < 10; ++i) s = fmaf(pdp_w1[o * 276 + 256 + i], xu[i], s);
        #pragma unroll
        for (int i = 0; i < 10; ++i) s = fmaf(pdp_w1[o * 276 + 266 + i], xl[i], s);
        t[o] = fmaxf(s, 0.f);
    }
    // dp = relu(gconv(t, pdp_w2)); dp_u = dp[0:10], dp_l = dp[10:20]
    float dpv[20];
    #pragma unroll
    for (int g = 0; g < 2; ++g) {
        #pragma unroll
        for (int o = 0; o < 10; ++o) {
            float s = 0.f;
            #pragma unroll
            for (int i = 0; i < 10; ++i)
                s = fmaf(pdp_w2[(g * 10 + o) * 10 + i], t[g * 10 + i], s);
            dpv[g * 10 + o] = fmaxf(s, 0.f);
        }
    }

    // ---------------- a = sigmoid(gconv([xu,xl], att_w, att_b)) -------------
    float au_s = att_b[0], al_s = att_b[1];
    #pragma unroll
    for (int i = 0; i < 10; ++i) {
        au_s = fmaf(att_w[i], xu[i], au_s);
        al_s = fmaf(att_w[10 + i], xl[i], al_s);
    }
    const float au = sigm(au_s), al = sigm(al_s);

    // ---------------- decomp attention scalars: [h_fea | xf | xh] -----------
    float su = dU + dU_ab[0];
    float sl = dL + dL_ab[0];
    #pragma unroll
    for (int i = 0; i < 10; ++i) { su = fmaf(dU_aw[256 + i], xv[i], su); sl = fmaf(dL_aw[256 + i], xv[i], sl); }
    #pragma unroll
    for (int i = 0; i < 10; ++i) { su = fmaf(dU_aw[266 + i], xu[i], su); sl = fmaf(dL_aw[266 + i], xl[i], sl); }
    const float attU = sigm(su), attL = sigm(sl);

    // xfh = relu(att * (W @ xf))
    float xfhu[10], xfhl[10];
    #pragma unroll
    for (int o = 0; o < 10; ++o) {
        float a = 0.f, b = 0.f;
        #pragma unroll
        for (int i = 0; i < 10; ++i) {
            a = fmaf(dU_w[o * 10 + i], xv[i], a);
            b = fmaf(dL_w[o * 10 + i], xv[i], b);
        }
        xfhu[o] = fmaxf(attU * a, 0.f);
        xfhl[o] = fmaxf(attL * b, 0.f);
    }

    // ---------------- comp U (xp[0:4]) --------------------------------------
    float msgU[10];
    #pragma unroll
    for (int i = 0; i < 10; ++i) msgU[i] = 0.f;
    #pragma unroll
    for (int pp = 0; pp < 4; ++pp) {
        const float* xq = xpg + (size_t)(pp * 8 + n) * 10 * HW + hw;
        float v[10];
        #pragma unroll
        for (int i = 0; i < 10; ++i) v[i] = xq[i * HW];
        float s = cU_ab[pp];
        #pragma unroll
        for (int i = 0; i < 10; ++i) s = fmaf(cU_aw[pp * 10 + i], v[i], s);
        float ca = sigm(s);
        #pragma unroll
        for (int i = 0; i < 10; ++i) msgU[i] = fmaf(ca, v[i], msgU[i]);
    }
    float xphu[10];
    #pragma unroll
    for (int o = 0; o < 10; ++o) {
        float s = 0.f;
        #pragma unroll
        for (int i = 0; i < 10; ++i) s = fmaf(cU_w[o * 20 + i], xu[i], s);
        #pragma unroll
        for (int i = 0; i < 10; ++i) s = fmaf(cU_w[o * 20 + 10 + i], msgU[i], s);
        xphu[o] = fmaxf(s, 0.f);
    }

    // ---------------- comp L (xp[4:6]) --------------------------------------
    float msgL[10];
    #pragma unroll
    for (int i = 0; i < 10; ++i) msgL[i] = 0.f;
    #pragma unroll
    for (int pp = 4; pp < 6; ++pp) {
        const float* xq = xpg + (size_t)(pp * 8 + n) * 10 * HW + hw;
        float v[10];
        #pragma unroll
        for (int i = 0; i < 10; ++i) v[i] = xq[i * HW];
        float s = cL_ab[pp - 4];
        #pragma unroll
        for (int i = 0; i < 10; ++i) s = fmaf(cL_aw[(pp - 4) * 10 + i], v[i], s);
        float ca = sigm(s);
        #pragma unroll
        for (int i = 0; i < 10; ++i) msgL[i] = fmaf(ca, v[i], msgL[i]);
    }
    float xphl[10];
    #pragma unroll
    for (int o = 0; o < 10; ++o) {
        float s = 0.f;
        #pragma unroll
        for (int i = 0; i < 10; ++i) s = fmaf(cL_w[o * 20 + i], xl[i], s);
        #pragma unroll
        for (int i = 0; i < 10; ++i) s = fmaf(cL_w[o * 20 + 10 + i], msgL[i], s);
        xphl[o] = fmaxf(s, 0.f);
    }

    // ---------------- updates ----------------------------------------------
    float outU[10], outL[10];
    {
        float m[10];
        #pragma unroll
        for (int i = 0; i < 10; ++i)
            m[i] = xphu[i] + (dpv[10 + i] * al + xu[i] * au) + xfhu[i];  // xlh
        #pragma unroll
        for (int o = 0; o < 10; ++o) {
            float gs = uU_gb[o], cs = 0.f;
            #pragma unroll
            for (int i = 0; i < 10; ++i) {
                gs = fmaf(uU_gw[o * 20 + i], xu[i], gs);
                cs = fmaf(uU_cw[o * 20 + i], xu[i], cs);
            }
            #pragma unroll
            for (int i = 0; i < 10; ++i) {
                gs = fmaf(uU_gw[o * 20 + 10 + i], m[i], gs);
                cs = fmaf(uU_cw[o * 20 + 10 + i], m[i], cs);
            }
            float g = sigm(gs), cd = fmaxf(cs, 0.f);
            outU[o] = xu[o] * (1.f - g) + cd * g;
        }
    }
    {
        float m[10];
        #pragma unroll
        for (int i = 0; i < 10; ++i)
            m[i] = xphl[i] + (dpv[i] * au + xl[i] * al) + xfhl[i];       // xuh
        #pragma unroll
        for (int o = 0; o < 10; ++o) {
            float gs = uL_gb[o], cs = 0.f;
            #pragma unroll
            for (int i = 0; i < 10; ++i) {
                gs = fmaf(uL_gw[o * 20 + i], xl[i], gs);
                cs = fmaf(uL_cw[o * 20 + i], xl[i], cs);
            }
            #pragma unroll
            for (int i = 0; i < 10; ++i) {
                gs = fmaf(uL_gw[o * 20 + 10 + i], m[i], gs);
                cs = fmaf(uL_cw[o * 20 + 10 + i], m[i], cs);
            }
            float g = sigm(gs), cd = fmaxf(cs, 0.f);
            outL[o] = xl[o] * (1.f - g) + cd * g;
        }
    }

    // ---------------- stores: [xh_u_new | xh_l_new | att_u | att_l] (f32) ---
    {
        int baseU = n * 10 * HW + hw;
        #pragma unroll
        for (int c = 0; c < 10; ++c) out[baseU + c * HW] = outU[c];
        int baseL = 1310720 + baseU;
        #pragma unroll
        for (int c = 0; c < 10; ++c) out[baseL + c * HW] = outL[c];
        out[2621440 + n * HW + hw] = attU;
        out[2752512 + n * HW + hw] = attL;
    }
}

extern "C" void kernel_launch(void* const* d_in, const int* in_sizes, int n_in,
                              void* d_out, int out_size, void* d_ws, size_t ws_size,
                              hipStream_t stream) {
    (void)in_sizes; (void)n_in; (void)out_size; (void)d_ws; (void)ws_size;
    const float* hf   = (const float*)d_in[0];
    const float* xhu  = (const float*)d_in[1];
    const float* xhl  = (const float*)d_in[2];
    const float* xfg  = (const float*)d_in[3];
    const float* xpg  = (const float*)d_in[4];
    const float* w1   = (const float*)d_in[5];
    const float* w2   = (const float*)d_in[6];
    const float* aw   = (const float*)d_in[7];
    const float* ab   = (const float*)d_in[8];
    const float* cUaw = (const float*)d_in[9];
    const float* cUab = (const float*)d_in[10];
    const float* cUw  = (const float*)d_in[11];
    const float* cLaw = (const float*)d_in[12];
    const float* cLab = (const float*)d_in[13];
    const float* cLw  = (const float*)d_in[14];
    const float* dUaw = (const float*)d_in[15];
    const float* dUab = (const float*)d_in[16];
    const float* dUw  = (const float*)d_in[17];
    const float* dLaw = (const float*)d_in[18];
    const float* dLab = (const float*)d_in[19];
    const float* dLw  = (const float*)d_in[20];
    const float* uUgw = (const float*)d_in[21];
    const float* uUgb = (const float*)d_in[22];
    const float* uUcw = (const float*)d_in[23];
    const float* uLgw = (const float*)d_in[24];
    const float* uLgb = (const float*)d_in[25];
    const float* uLcw = (const float*)d_in[26];

    dim3 grid(NPIX / 64), block(256);   // 64 px per block, 4 waves split over channels
    hipLaunchKernelGGL(half_graph_fused, grid, block, 0, stream,
        hf, xhu, xhl, xfg, xpg, w1, w2, aw, ab,
        cUaw, cUab, cUw, cLaw, cLab, cLw,
        dUaw, dUab, dUw, dLaw, dLab, dLw,
        uUgw, uUgb, uUcw, uLgw, uLgb, uLcw,
        (float*)d_out);
}

// Round 6
// 296.730 us; speedup vs baseline: 1.3011x; 1.0244x over previous
//
#include <hip/hip_runtime.h>
#include <stdint.h>

typedef unsigned short u16;
typedef unsigned int   u32;

#define HW   16384      // 128*128
#define NPIX 131072     // 8 * HW

__device__ __forceinline__ float sigm(float x) { return 1.f / (1.f + __expf(-x)); }

// Broadcast lane cc's value to all lanes via SGPR (pure VALU; no LDS/VMEM).
__device__ __forceinline__ float rdlane(float v, int lane) {
    return __int_as_float(__builtin_amdgcn_readlane(__float_as_int(v), lane));
}

// R4 post-mortem: per-channel uniform weight loads flooded VMEM+addr-VALU (189us).
// R5 post-mortem: per-channel LDS broadcast reads are LDS-return-BW-bound
// (6 b128 x 8 waves ~= 384 cyc/CU/channel vs 88 cyc FMA; VALUBusy 19%, 132us).
// R6: weights delivered via registers + v_readlane: per 64-ch chunk each lane
// bulk-loads W[o][c0+lane] (22 coalesced loads, double-buffered), inner loop
// does readlane->SGPR + FMA(sgpr,vgpr). 1 px/thread; tail on all threads.
__global__ __launch_bounds__(256, 2) void half_graph_fused(
    const float* __restrict__ hf,  const float* __restrict__ xhu, const float* __restrict__ xhl,
    const float* __restrict__ xfg, const float* __restrict__ xpg,
    const float* __restrict__ pdp_w1, const float* __restrict__ pdp_w2,
    const float* __restrict__ att_w,  const float* __restrict__ att_b,
    const float* __restrict__ cU_aw, const float* __restrict__ cU_ab, const float* __restrict__ cU_w,
    const float* __restrict__ cL_aw, const float* __restrict__ cL_ab, const float* __restrict__ cL_w,
    const float* __restrict__ dU_aw, const float* __restrict__ dU_ab, const float* __restrict__ dU_w,
    const float* __restrict__ dL_aw, const float* __restrict__ dL_ab, const float* __restrict__ dL_w,
    const float* __restrict__ uU_gw, const float* __restrict__ uU_gb, const float* __restrict__ uU_cw,
    const float* __restrict__ uL_gw, const float* __restrict__ uL_gb, const float* __restrict__ uL_cw,
    float* __restrict__ out)
{
    const int p  = blockIdx.x * blockDim.x + threadIdx.x;   // pixel id
    const int n  = p >> 14;            // batch (wave-uniform)
    const int hw = p & 16383;          // spatial (lane-contiguous)
    const int ln = threadIdx.x & 63;   // lane

    // ---- hoist small per-pixel vectors: latency hides under the matvec ----
    float xu[10], xl[10], xv[10];
    {
        const float* a = xhu + (size_t)n * 10 * HW + hw;
        const float* b = xhl + (size_t)n * 10 * HW + hw;
        const float* c = xfg + (size_t)n * 10 * HW + hw;
        #pragma unroll
        for (int i = 0; i < 10; ++i) xu[i] = a[i * HW];
        #pragma unroll
        for (int i = 0; i < 10; ++i) xl[i] = b[i * HW];
        #pragma unroll
        for (int i = 0; i < 10; ++i) xv[i] = c[i * HW];
    }

    // ---- big matvec: 22 dots of length 256 (20 pdp rows + dU/dL att rows) --
    const float* hfp = hf + (size_t)n * 256 * HW + hw;

    float acc[22];
    #pragma unroll
    for (int o = 0; o < 22; ++o) acc[o] = 0.f;

    float wA[22], wB[22];
    auto prefetch = [&](float (&w)[22], int c0) {
        #pragma unroll
        for (int o = 0; o < 20; ++o) w[o] = pdp_w1[o * 276 + c0 + ln];  // coalesced 256B/wave
        w[20] = dU_aw[c0 + ln];
        w[21] = dL_aw[c0 + ln];
    };
    auto compute = [&](const float (&w)[22], int c0) {
        const float* xp0 = hfp + (size_t)c0 * HW;
        #pragma unroll 8
        for (int cc = 0; cc < 64; ++cc) {
            float x = xp0[cc * HW];                 // coalesced 256B/wave
            #pragma unroll
            for (int o = 0; o < 22; ++o)
                acc[o] = fmaf(rdlane(w[o], cc), x, acc[o]);   // SGPR x VGPR FMA
        }
    };

    prefetch(wA, 0);
    prefetch(wB, 64);
    compute(wA, 0);
    prefetch(wA, 128);
    compute(wB, 64);
    prefetch(wB, 192);
    compute(wA, 128);
    compute(wB, 192);

    const float dU = acc[20], dL = acc[21];

    // ---------------- pdp: t = relu(W1 @ [hf,xu,xl]) ------------------------
    float t[20];
    #pragma unroll
    for (int o = 0; o < 20; ++o) {
        float s = acc[o];
        #pragma unroll
        for (int i = 0; i < 10; ++i) s = fmaf(pdp_w1[o * 276 + 256 + i], xu[i], s);
        #pragma unroll
        for (int i = 0; i < 10; ++i) s = fmaf(pdp_w1[o * 276 + 266 + i], xl[i], s);
        t[o] = fmaxf(s, 0.f);
    }
    // dp = relu(gconv(t, pdp_w2)); dp_u = dp[0:10], dp_l = dp[10:20]
    float dpv[20];
    #pragma unroll
    for (int g = 0; g < 2; ++g) {
        #pragma unroll
        for (int o = 0; o < 10; ++o) {
            float s = 0.f;
            #pragma unroll
            for (int i = 0; i < 10; ++i)
                s = fmaf(pdp_w2[(g * 10 + o) * 10 + i], t[g * 10 + i], s);
            dpv[g * 10 + o] = fmaxf(s, 0.f);
        }
    }

    // ---------------- a = sigmoid(gconv([xu,xl], att_w, att_b)) -------------
    float au_s = att_b[0], al_s = att_b[1];
    #pragma unroll
    for (int i = 0; i < 10; ++i) {
        au_s = fmaf(att_w[i], xu[i], au_s);
        al_s = fmaf(att_w[10 + i], xl[i], al_s);
    }
    const float au = sigm(au_s), al = sigm(al_s);

    // ---------------- decomp attention scalars: [h_fea | xf | xh] -----------
    float su = dU + dU_ab[0];
    float sl = dL + dL_ab[0];
    #pragma unroll
    for (int i = 0; i < 10; ++i) { su = fmaf(dU_aw[256 + i], xv[i], su); sl = fmaf(dL_aw[256 + i], xv[i], sl); }
    #pragma unroll
    for (int i = 0; i < 10; ++i) { su = fmaf(dU_aw[266 + i], xu[i], su); sl = fmaf(dL_aw[266 + i], xl[i], sl); }
    const float attU = sigm(su), attL = sigm(sl);

    // xfh = relu(att * (W @ xf))
    float xfhu[10], xfhl[10];
    #pragma unroll
    for (int o = 0; o < 10; ++o) {
        float a = 0.f, b = 0.f;
        #pragma unroll
        for (int i = 0; i < 10; ++i) {
            a = fmaf(dU_w[o * 10 + i], xv[i], a);
            b = fmaf(dL_w[o * 10 + i], xv[i], b);
        }
        xfhu[o] = fmaxf(attU * a, 0.f);
        xfhl[o] = fmaxf(attL * b, 0.f);
    }

    // ---------------- comp U (xp[0:4]) --------------------------------------
    float msgU[10];
    #pragma unroll
    for (int i = 0; i < 10; ++i) msgU[i] = 0.f;
    #pragma unroll
    for (int pp = 0; pp < 4; ++pp) {
        const float* xq = xpg + (size_t)(pp * 8 + n) * 10 * HW + hw;
        float v[10];
        #pragma unroll
        for (int i = 0; i < 10; ++i) v[i] = xq[i * HW];
        float s = cU_ab[pp];
        #pragma unroll
        for (int i = 0; i < 10; ++i) s = fmaf(cU_aw[pp * 10 + i], v[i], s);
        float ca = sigm(s);
        #pragma unroll
        for (int i = 0; i < 10; ++i) msgU[i] = fmaf(ca, v[i], msgU[i]);
    }
    float xphu[10];
    #pragma unroll
    for (int o = 0; o < 10; ++o) {
        float s = 0.f;
        #pragma unroll
        for (int i = 0; i < 10; ++i) s = fmaf(cU_w[o * 20 + i], xu[i], s);
        #pragma unroll
        for (int i = 0; i < 10; ++i) s = fmaf(cU_w[o * 20 + 10 + i], msgU[i], s);
        xphu[o] = fmaxf(s, 0.f);
    }

    // ---------------- comp L (xp[4:6]) --------------------------------------
    float msgL[10];
    #pragma unroll
    for (int i = 0; i < 10; ++i) msgL[i] = 0.f;
    #pragma unroll
    for (int pp = 4; pp < 6; ++pp) {
        const float* xq = xpg + (size_t)(pp * 8 + n) * 10 * HW + hw;
        float v[10];
        #pragma unroll
        for (int i = 0; i < 10; ++i) v[i] = xq[i * HW];
        float s = cL_ab[pp - 4];
        #pragma unroll
        for (int i = 0; i < 10; ++i) s = fmaf(cL_aw[(pp - 4) * 10 + i], v[i], s);
        float ca = sigm(s);
        #pragma unroll
        for (int i = 0; i < 10; ++i) msgL[i] = fmaf(ca, v[i], msgL[i]);
    }
    float xphl[10];
    #pragma unroll
    for (int o = 0; o < 10; ++o) {
        float s = 0.f;
        #pragma unroll
        for (int i = 0; i < 10; ++i) s = fmaf(cL_w[o * 20 + i], xl[i], s);
        #pragma unroll
        for (int i = 0; i < 10; ++i) s = fmaf(cL_w[o * 20 + 10 + i], msgL[i], s);
        xphl[o] = fmaxf(s, 0.f);
    }

    // ---------------- updates ----------------------------------------------
    float outU[10], outL[10];
    {
        float m[10];
        #pragma unroll
        for (int i = 0; i < 10; ++i)
            m[i] = xphu[i] + (dpv[10 + i] * al + xu[i] * au) + xfhu[i];  // xlh
        #pragma unroll
        for (int o = 0; o < 10; ++o) {
            float gs = uU_gb[o], cs = 0.f;
            #pragma unroll
            for (int i = 0; i < 10; ++i) {
                gs = fmaf(uU_gw[o * 20 + i], xu[i], gs);
                cs = fmaf(uU_cw[o * 20 + i], xu[i], cs);
            }
            #pragma unroll
            for (int i = 0; i < 10; ++i) {
                gs = fmaf(uU_gw[o * 20 + 10 + i], m[i], gs);
                cs = fmaf(uU_cw[o * 20 + 10 + i], m[i], cs);
            }
            float g = sigm(gs), cd = fmaxf(cs, 0.f);
            outU[o] = xu[o] * (1.f - g) + cd * g;
        }
    }
    {
        float m[10];
        #pragma unroll
        for (int i = 0; i < 10; ++i)
            m[i] = xphl[i] + (dpv[i] * au + xl[i] * al) + xfhl[i];       // xuh
        #pragma unroll
        for (int o = 0; o < 10; ++o) {
            float gs = uL_gb[o], cs = 0.f;
            #pragma unroll
            for (int i = 0; i < 10; ++i) {
                gs = fmaf(uL_gw[o * 20 + i], xl[i], gs);
                cs = fmaf(uL_cw[o * 20 + i], xl[i], cs);
            }
            #pragma unroll
            for (int i = 0; i < 10; ++i) {
                gs = fmaf(uL_gw[o * 20 + 10 + i], m[i], gs);
                cs = fmaf(uL_cw[o * 20 + 10 + i], m[i], cs);
            }
            float g = sigm(gs), cd = fmaxf(cs, 0.f);
            outL[o] = xl[o] * (1.f - g) + cd * g;
        }
    }

    // ---------------- stores: [xh_u_new | xh_l_new | att_u | att_l] (f32) ---
    {
        int baseU = n * 10 * HW + hw;
        #pragma unroll
        for (int c = 0; c < 10; ++c) out[baseU + c * HW] = outU[c];
        int baseL = 1310720 + baseU;
        #pragma unroll
        for (int c = 0; c < 10; ++c) out[baseL + c * HW] = outL[c];
        out[2621440 + n * HW + hw] = attU;
        out[2752512 + n * HW + hw] = attL;
    }
}

extern "C" void kernel_launch(void* const* d_in, const int* in_sizes, int n_in,
                              void* d_out, int out_size, void* d_ws, size_t ws_size,
                              hipStream_t stream) {
    (void)in_sizes; (void)n_in; (void)out_size; (void)d_ws; (void)ws_size;
    const float* hf   = (const float*)d_in[0];
    const float* xhu  = (const float*)d_in[1];
    const float* xhl  = (const float*)d_in[2];
    const float* xfg  = (const float*)d_in[3];
    const float* xpg  = (const float*)d_in[4];
    const float* w1   = (const float*)d_in[5];
    const float* w2   = (const float*)d_in[6];
    const float* aw   = (const float*)d_in[7];
    const float* ab   = (const float*)d_in[8];
    const float* cUaw = (const float*)d_in[9];
    const float* cUab = (const float*)d_in[10];
    const float* cUw  = (const float*)d_in[11];
    const float* cLaw = (const float*)d_in[12];
    const float* cLab = (const float*)d_in[13];
    const float* cLw  = (const float*)d_in[14];
    const float* dUaw = (const float*)d_in[15];
    const float* dUab = (const float*)d_in[16];
    const float* dUw  = (const float*)d_in[17];
    const float* dLaw = (const float*)d_in[18];
    const float* dLab = (const float*)d_in[19];
    const float* dLw  = (const float*)d_in[20];
    const float* uUgw = (const float*)d_in[21];
    const float* uUgb = (const float*)d_in[22];
    const float* uUcw = (const float*)d_in[23];
    const float* uLgw = (const float*)d_in[24];
    const float* uLgb = (const float*)d_in[25];
    const float* uLcw = (const float*)d_in[26];

    dim3 grid(NPIX / 256), block(256);   // 1 px/thread
    hipLaunchKernelGGL(half_graph_fused, grid, block, 0, stream,
        hf, xhu, xhl, xfg, xpg, w1, w2, aw, ab,
        cUaw, cUab, cUw, cLaw, cLab, cLw,
        dUaw, dUab, dUw, dLaw, dLab, dLw,
        uUgw, uUgb, uUcw, uLgw, uLgb, uLcw,
        (float*)d_out);
}